// Round 2
// baseline (575.594 us; speedup 1.0000x reference)
//
#include <hip/hip_runtime.h>

typedef unsigned short ushort_t;
typedef float  f32x4   __attribute__((ext_vector_type(4)));
typedef float  f32x16  __attribute__((ext_vector_type(16)));
typedef __bf16 bf16x4  __attribute__((ext_vector_type(4)));
typedef __bf16 bf16x8  __attribute__((ext_vector_type(8)));

#define MFMA16(a,b,c) __builtin_amdgcn_mfma_f32_16x16x32_bf16((a),(b),(c),0,0,0)
#define MFMA32(a,b,c) __builtin_amdgcn_mfma_f32_32x32x16_bf16((a),(b),(c),0,0,0)

__device__ __forceinline__ ushort_t f2bf(float f) {
  union { float f; unsigned u; } v; v.f = f;
  unsigned u = v.u;
  unsigned r = u + 0x7FFFu + ((u >> 16) & 1u);   // round-to-nearest-even
  return (ushort_t)(r >> 16);
}
__device__ __forceinline__ float bf2f(ushort_t s) {
  union { unsigned u; float f; } v; v.u = ((unsigned)s) << 16;
  return v.f;
}

// async global->LDS, 16B per lane. LDS dest is wave-uniform-base + lane*16;
// global src is per-lane (this is how the source-side swizzle is applied).
__device__ __forceinline__ void gload_lds16(const ushort_t* g, ushort_t* l) {
  __builtin_amdgcn_global_load_lds(
      (const __attribute__((address_space(1))) unsigned int*)g,
      (__attribute__((address_space(3))) unsigned int*)l, 16, 0, 0);
}

// ---------------------------------------------------------------------------
// Kernel 1: fused grouped conv (MFMA) + bias; x staged once per block (f32 ->
// bf16 transpose in LDS), loops 3 branches x 4 ngsub. Writes unnormalized y
// in final layouts; accumulates GroupNorm partial sums via atomics.
// grid (pc=16, g*b=64), 256 thr.
// Q branch -> [B][C][P]; K/V branches -> [B][H][P][128].
// R7: Q-branch MFMA operand swap (C gets co on lanes, p on regs) so ALL yl
// writes pack bf16x4 along the fast axis; wl staging writes vectorized.
// ---------------------------------------------------------------------------
__global__ __launch_bounds__(256) void conv_gn(
    const float* __restrict__ x,
    const float* __restrict__ wq, const float* __restrict__ wk, const float* __restrict__ wv,
    const float* __restrict__ bq, const float* __restrict__ bk, const float* __restrict__ bv,
    ushort_t* __restrict__ Qb, ushort_t* __restrict__ Kb, ushort_t* __restrict__ Vb,
    float* __restrict__ stats) {
  int pc = blockIdx.x;
  int gz = blockIdx.y;
  int b = gz & 7, g = gz >> 3;
  int tid = threadIdx.x, lane = tid & 63, wid = tid >> 6;
  int l15 = lane & 15, q = lane >> 4;

  __shared__ __align__(16) ushort_t xl[128 * 72];   // [p][f]
  __shared__ __align__(16) ushort_t wl[128 * 72];   // [co][f], one branch
  __shared__ __align__(16) ushort_t yl[128 * 40];   // staging (br=0 uses [32][136])
  __shared__ float biasl[128];
  __shared__ float redbuf[8];

  // stage x tile [64 f][128 p] f32 -> xl[p][f] bf16
  const float* xsrc = x + ((size_t)(b * 512 + g * 64)) * 2048 + pc * 128;
#pragma unroll
  for (int r = 0; r < 8; ++r) {
    int chunk = tid + 256 * r;
    int c = chunk >> 5, p4 = chunk & 31;
    float4 v = *(const float4*)&xsrc[(size_t)c * 2048 + p4 * 4];
    xl[(p4 * 4 + 0) * 72 + c] = f2bf(v.x);
    xl[(p4 * 4 + 1) * 72 + c] = f2bf(v.y);
    xl[(p4 * 4 + 2) * 72 + c] = f2bf(v.z);
    xl[(p4 * 4 + 3) * 72 + c] = f2bf(v.w);
  }
  __syncthreads();

  // resident B-frags (wave's 32 p-cols)
  bf16x8 Bx[2][2];
#pragma unroll
  for (int n2 = 0; n2 < 2; ++n2)
#pragma unroll
    for (int kk = 0; kk < 2; ++kk)
      Bx[n2][kk] = *(const bf16x8*)&xl[((wid * 2 + n2) * 16 + l15) * 72 + kk * 32 + q * 8];

  for (int br = 0; br < 3; ++br) {
    const float* w    = (br == 0) ? wq : ((br == 1) ? wk : wv);
    const float* bias = (br == 0) ? bq : ((br == 1) ? bk : bv);
    ushort_t* dst     = (br == 0) ? Qb : ((br == 1) ? Kb : Vb);
    __syncthreads();   // previous branch's wl/yl consumers done
    const float* wsrc = w + (size_t)g * 128 * 64;
#pragma unroll
    for (int r = 0; r < 8; ++r) {
      int idx = (tid + 256 * r) << 2;
      float4 v = *(const float4*)&wsrc[idx];
      int row = idx >> 6, f = idx & 63;
      bf16x4 wv4 = {(__bf16)v.x, (__bf16)v.y, (__bf16)v.z, (__bf16)v.w};
      *(bf16x4*)&wl[row * 72 + f] = wv4;
    }
    if (tid < 128) biasl[tid] = bias[g * 128 + tid];
    __syncthreads();

    for (int ngs = 0; ngs < 4; ++ngs) {
      int co0 = ngs * 32;
      bf16x8 Aw[2][2];
#pragma unroll
      for (int m = 0; m < 2; ++m)
#pragma unroll
        for (int kk = 0; kk < 2; ++kk)
          Aw[m][kk] = *(const bf16x8*)&wl[(co0 + m * 16 + l15) * 72 + kk * 32 + q * 8];
      // acc[a][b]: br==0 (swapped): a = n2 (p-tile), b = mw (co-tile);
      //            br>=1:           a = m  (co),     b = n2 (p)
      f32x4 acc[2][2];
#pragma unroll
      for (int a = 0; a < 2; ++a)
#pragma unroll
        for (int c2 = 0; c2 < 2; ++c2) acc[a][c2] = (f32x4){0.f, 0.f, 0.f, 0.f};
      if (br == 0) {
#pragma unroll
        for (int kk = 0; kk < 2; ++kk)
#pragma unroll
          for (int n2 = 0; n2 < 2; ++n2)
#pragma unroll
            for (int mw = 0; mw < 2; ++mw)
              acc[n2][mw] = MFMA16(Bx[n2][kk], Aw[mw][kk], acc[n2][mw]);
      } else {
#pragma unroll
        for (int kk = 0; kk < 2; ++kk)
#pragma unroll
          for (int n2 = 0; n2 < 2; ++n2)
#pragma unroll
            for (int m = 0; m < 2; ++m)
              acc[m][n2] = MFMA16(Aw[m][kk], Bx[n2][kk], acc[m][n2]);
      }

      float s1 = 0.f, s2 = 0.f;
      if (br == 0) {   // c = co0 + mw*16 + l15 (one bias per frag)
#pragma unroll
        for (int n2 = 0; n2 < 2; ++n2)
#pragma unroll
          for (int mw = 0; mw < 2; ++mw) {
            float bi = biasl[co0 + mw * 16 + l15];
#pragma unroll
            for (int rg = 0; rg < 4; ++rg) {
              float y = acc[n2][mw][rg] + bi;
              acc[n2][mw][rg] = y;
              s1 += y; s2 += y * y;
            }
          }
      } else {         // c = co0 + m*16 + 4q + rg
#pragma unroll
        for (int m = 0; m < 2; ++m)
#pragma unroll
          for (int n2 = 0; n2 < 2; ++n2)
#pragma unroll
            for (int rg = 0; rg < 4; ++rg) {
              float y = acc[m][n2][rg] + biasl[co0 + m * 16 + 4 * q + rg];
              acc[m][n2][rg] = y;
              s1 += y; s2 += y * y;
            }
      }
#pragma unroll
      for (int mask = 32; mask >= 1; mask >>= 1) {
        s1 += __shfl_xor(s1, mask, 64);
        s2 += __shfl_xor(s2, mask, 64);
      }

      __syncthreads();   // previous ngs's yl global-store reads done
      if (lane == 0) { redbuf[wid * 2] = s1; redbuf[wid * 2 + 1] = s2; }
      if (br == 0) {   // yl: [32 c][136 p]; row = co_local (l15), cols = p (regs)
#pragma unroll
        for (int n2 = 0; n2 < 2; ++n2)
#pragma unroll
          for (int mw = 0; mw < 2; ++mw) {
            bf16x4 pk = {(__bf16)acc[n2][mw][0], (__bf16)acc[n2][mw][1],
                         (__bf16)acc[n2][mw][2], (__bf16)acc[n2][mw][3]};
            *(bf16x4*)&yl[(mw * 16 + l15) * 136 + (wid * 2 + n2) * 16 + 4 * q] = pk;
          }
      } else {         // yl: [128 p][40 c]; row = p (l15), cols = c (regs)
#pragma unroll
        for (int m = 0; m < 2; ++m)
#pragma unroll
          for (int n2 = 0; n2 < 2; ++n2) {
            bf16x4 pk = {(__bf16)acc[m][n2][0], (__bf16)acc[m][n2][1],
                         (__bf16)acc[m][n2][2], (__bf16)acc[m][n2][3]};
            *(bf16x4*)&yl[((wid * 2 + n2) * 16 + l15) * 40 + m * 16 + 4 * q] = pk;
          }
      }
      __syncthreads();

      if (br == 0) {
#pragma unroll
        for (int r = 0; r < 2; ++r) {
          int chunk = tid + 256 * r;
          int row = chunk >> 4, ch = chunk & 15;
          *(uint4*)&dst[((size_t)(b * 1024 + g * 128 + co0 + row)) * 2048 + pc * 128 + ch * 8] =
              *(const uint4*)&yl[row * 136 + ch * 8];
        }
      } else {
#pragma unroll
        for (int r = 0; r < 2; ++r) {
          int chunk = tid + 256 * r;
          int row = chunk >> 2, ch = chunk & 3;
          *(uint4*)&dst[((size_t)(b * 8 + g) * 2048 + pc * 128 + row) * 128 + co0 + ch * 8] =
              *(const uint4*)&yl[row * 40 + ch * 8];
        }
      }
      if (tid == 0) {
        float S1 = redbuf[0] + redbuf[2] + redbuf[4] + redbuf[6];
        float S2 = redbuf[1] + redbuf[3] + redbuf[5] + redbuf[7];
        int sidx = (br * 8 + b) * 32 + g * 4 + ngs;
        atomicAdd(&stats[2 * sidx], S1);
        atomicAdd(&stats[2 * sidx + 1], S2);
      }
    }
  }
}

// ---------------------------------------------------------------------------
// Kernel 2: in-place GroupNorm affine + LeakyReLU over the 3 contiguous bufs.
// R7: grid-stride (2048 blocks x 12 iters) for full occupancy + MLP.
// ---------------------------------------------------------------------------
__global__ __launch_bounds__(256) void gn_apply(
    ushort_t* __restrict__ buf, const float* __restrict__ stats,
    const float* __restrict__ gw1, const float* __restrict__ gb1,
    const float* __restrict__ gw2, const float* __restrict__ gb2,
    const float* __restrict__ gw3, const float* __restrict__ gb3) {
  const unsigned NQ = 16777216u;
  unsigned base = blockIdx.x * 256 + threadIdx.x;   // 524288 threads
  for (int itn = 0; itn < 12; ++itn) {
    unsigned gid = base + (unsigned)itn * 524288u;
    unsigned e = gid * 8;
    int br; unsigned local;
    if (e < NQ)            { br = 0; local = e; }
    else if (e < 2u * NQ)  { br = 1; local = e - NQ; }
    else                   { br = 2; local = e - 2u * NQ; }
    int b, c0;
    if (br == 0) { b = local >> 21; c0 = (local >> 11) & 1023; }
    else {
      int cih = local & 127; int h = (local >> 18) & 7;
      b = local >> 21; c0 = h * 128 + cih;
    }
    int ng = c0 >> 5;
    const float* gw = (br == 0) ? gw1 : ((br == 1) ? gw2 : gw3);
    const float* gb = (br == 0) ? gb1 : ((br == 1) ? gb2 : gb3);
    int sidx = (br * 8 + b) * 32 + ng;
    float mean = stats[2 * sidx] * (1.f / 65536.f);
    float var  = stats[2 * sidx + 1] * (1.f / 65536.f) - mean * mean;
    float rstd = rsqrtf(var + 1e-5f);
    uint4 d = *(uint4*)&buf[(size_t)e];
    ushort_t* pu = (ushort_t*)&d;
#pragma unroll
    for (int i = 0; i < 8; ++i) {
      int ci = (br == 0) ? c0 : (c0 + i);
      float a = rstd * gw[ci];
      float b2 = gb[ci] - mean * a;
      float yn = fmaf(bf2f(pu[i]), a, b2);
      yn = (yn >= 0.f) ? yn : 0.1f * yn;
      pu[i] = f2bf(yn);
    }
    *(uint4*)&buf[(size_t)e] = d;
  }
}

// ---------------------------------------------------------------------------
// Kernel 3: flash attention, 32x32x16 MFMA, S^T formulation.
// flashQ=K-branch [B,H,P,128] (i), flashK=V-branch [B,H,P,128] (j),
// flashV=Q-branch [B,C,P] (c rows, p=j cols).
//
// R7 vs 204us version (grid-capped occupancy 2 blk/CU; FETCH 2.85x ideal
// from XCD-L2 thrash since the 8 it-blocks sharing fK/fV landed on 8 XCDs):
//  * grid (x=bh=64, y=it): linear id = bh + 64*it -> XCD = bh&7, so ALL
//    it-blocks of one bh share one XCD's L2 (T1).
//  * i-tile 256 -> 128 (4 waves x 32 i each): grid 1024 = EXACTLY 4
//    blocks/CU (zero tail), 16 waves/CU. LDS trimmed to 40KB exactly
//    (2x8K fKs + 2x8K Vs + 8K Ps) so 4 blocks fit; __launch_bounds__(256,4)
//    caps VGPR at 128.
//  * Ps: stride 32 (no pad) + 16B-unit XOR swizzle u^=(row^(row>>2))&3:
//    conflict-free b128 reads, 2-way b64 writes.
//  * kept: dbuf prefetch via global_load_lds (1 barrier/jt), source-side
//    XOR swizzles for fKs/Vs, defer-max, exp2-domain softmax, cvt_pk packs.
// ---------------------------------------------------------------------------
__global__ __launch_bounds__(256, 4) void attn(
    const ushort_t* __restrict__ Qb, const ushort_t* __restrict__ Kb,
    const ushort_t* __restrict__ Vb, float* __restrict__ out) {
  __shared__ __align__(16) ushort_t fKs[2][32 * 128];   // [j][d] linear, 2x8192 B
  __shared__ __align__(16) ushort_t Vs[2][128 * 32];    // [c][j] linear, 2x8192 B
  __shared__ __align__(16) ushort_t Ps[128 * 32];       // [i][j] swizzled, 8192 B

  int bh = blockIdx.x, it = blockIdx.y;
  int b = bh >> 3, h = bh & 7;
  int tid = threadIdx.x, lane = tid & 63, wid = tid >> 6;
  int l31 = lane & 31, q2 = lane >> 5;
  // scale*log2(e): softmax in exp2 domain
  const float sl = 0.08838834764831845f * 1.4426950408889634f;

  // resident fQ B-frags: B[k=d][n=i], n-col = l31 -> row i (one-time load)
  bf16x8 Bq[8];
  {
    const ushort_t* fQp =
        Kb + ((size_t)bh * 2048 + it * 128 + wid * 32 + l31) * 128 + q2 * 8;
#pragma unroll
    for (int dc = 0; dc < 8; ++dc) Bq[dc] = *(const bf16x8*)&fQp[dc * 16];
  }

  float m2 = -3e38f, l_i = 0.f;
  f32x16 O[4];
#pragma unroll
  for (int mt = 0; mt < 4; ++mt) O[mt] = (f32x16)(0.f);

  const ushort_t* fKg = Vb + (size_t)bh * 2048 * 128;
  const ushort_t* fVg = Qb + ((size_t)(b * 1024 + h * 128)) * 2048;

  int prow = wid * 32 + l31;                       // this thread's P row (i)
  int pswz = (prow ^ (prow >> 2)) & 3;             // Ps 16B-unit swizzle

  // ---- staging: 512 16B-units per tensor-tile; each thread issues 2+2.
  // LDS is linear in unit index n (wave-uniform base + lane*16); the XOR
  // swizzle is applied to the unit index on the GLOBAL side.
#define STAGE(JT, NB)                                                          \
  do {                                                                         \
    _Pragma("unroll")                                                          \
    for (int r = 0; r < 2; ++r) {                                              \
      int n = tid + 256 * r;                                                   \
      int kr = n >> 4, ku = (n & 15) ^ (kr & 7);                               \
      gload_lds16(fKg + (size_t)(JT) * 4096 + kr * 128 + ku * 8,               \
                  &fKs[NB][n * 8]);                                            \
      int vr = n >> 2, vu = (n & 3) ^ ((vr >> 1) & 3);                         \
      gload_lds16(fVg + (size_t)vr * 2048 + (JT) * 32 + vu * 8,                \
                  &Vs[NB][n * 8]);                                             \
    }                                                                          \
  } while (0)

  STAGE(0, 0);
  __syncthreads();   // vmcnt(0) drain + barrier: tile 0 visible
  int cur = 0;

  for (int jt = 0; jt < 64; ++jt) {
    if (jt < 63) STAGE(jt + 1, cur ^ 1);   // async prefetch into idle buffer

    // S^T = fK . fQ^T : 8 swizzled A-reads, 8 MFMAs
    f32x16 ST = (f32x16)(0.f);
#pragma unroll
    for (int dc = 0; dc < 8; ++dc) {
      int up = (dc * 2 + q2) ^ (l31 & 7);
      bf16x8 Ak = *(const bf16x8*)&fKs[cur][l31 * 128 + up * 8];
      ST = MFMA32(Ak, Bq[dc], ST);
    }

    // online softmax over j; lane covers i = prow (j split across q2)
    {
      float vm[8];
#pragma unroll
      for (int r = 0; r < 8; ++r) vm[r] = fmaxf(ST[2 * r], ST[2 * r + 1]);
#pragma unroll
      for (int r = 0; r < 4; ++r) vm[r] = fmaxf(vm[r], vm[r + 4]);
      float vmax = fmaxf(fmaxf(vm[0], vm[1]), fmaxf(vm[2], vm[3]));
      float v2 = vmax * sl;
      v2 = fmaxf(v2, __shfl_xor(v2, 32, 64));
      float al = 1.f;
      bool need = !__all(v2 <= m2 + 8.f);   // defer-max: wave-uniform
      if (need) {
        float mn2 = fmaxf(m2, v2);
        al = __builtin_amdgcn_exp2f(m2 - mn2);
        m2 = mn2;
      }
      float mn = m2;
      float rs = 0.f;
#pragma unroll
      for (int r = 0; r < 4; ++r) {
        float p0 = __builtin_amdgcn_exp2f(fmaf(ST[4 * r + 0], sl, -mn));
        float p1 = __builtin_amdgcn_exp2f(fmaf(ST[4 * r + 1], sl, -mn));
        float p2 = __builtin_amdgcn_exp2f(fmaf(ST[4 * r + 2], sl, -mn));
        float p3 = __builtin_amdgcn_exp2f(fmaf(ST[4 * r + 3], sl, -mn));
        rs += (p0 + p1) + (p2 + p3);
        bf16x4 pk = {(__bf16)p0, (__bf16)p1, (__bf16)p2, (__bf16)p3};
        // logical unit r (j = 8r + 4q2 + {0..3}), physical unit r^pswz
        *(bf16x4*)&Ps[prow * 32 + (r ^ pswz) * 8 + q2 * 4] = pk;
      }
      rs += __shfl_xor(rs, 32, 64);
      l_i = l_i * al + rs;
      if (need) {   // O rescale only when running max moved (i on lanes)
#pragma unroll
        for (int mt = 0; mt < 4; ++mt)
#pragma unroll
          for (int rg = 0; rg < 16; ++rg) O[mt][rg] *= al;
      }
    }

    // O^T += V . P^T : swizzled V-reads + P-reads (wave-private), 8 MFMAs
#pragma unroll
    for (int jc = 0; jc < 2; ++jc) {
      int pu = ((jc * 2 + q2) ^ pswz);
      bf16x8 Bp = *(const bf16x8*)&Ps[prow * 32 + pu * 8];
#pragma unroll
      for (int mt = 0; mt < 4; ++mt) {
        int row = mt * 32 + l31;
        int up = (jc * 2 + q2) ^ ((row >> 1) & 3);
        bf16x8 Av = *(const bf16x8*)&Vs[cur][row * 32 + up * 8];
        O[mt] = MFMA32(Av, Bp, O[mt]);
      }
    }
    __syncthreads();   // single barrier: prefetch complete + all reads done
    cur ^= 1;
  }
#undef STAGE

  // epilogue: i on lanes -> direct coalesced stores
  float linv = 1.f / l_i;
#pragma unroll
  for (int mt = 0; mt < 4; ++mt) {
    float* obase = out + ((size_t)(b * 1024 + h * 128 + mt * 32)) * 2048 +
                   it * 128 + wid * 32 + l31;
#pragma unroll
    for (int rg = 0; rg < 16; ++rg) {
      int c = (rg & 3) + 8 * (rg >> 2) + 4 * q2;
      obase[(size_t)c * 2048] = O[mt][rg] * linv;
    }
  }
}

// ---------------------------------------------------------------------------
extern "C" void kernel_launch(void* const* d_in, const int* in_sizes, int n_in,
                              void* d_out, int out_size, void* d_ws, size_t ws_size,
                              hipStream_t stream) {
  const float* x   = (const float*)d_in[0];
  const float* wq  = (const float*)d_in[1];
  const float* bq  = (const float*)d_in[2];
  const float* gw1 = (const float*)d_in[3];
  const float* gb1 = (const float*)d_in[4];
  const float* wk  = (const float*)d_in[5];
  const float* bk  = (const float*)d_in[6];
  const float* gw2 = (const float*)d_in[7];
  const float* gb2 = (const float*)d_in[8];
  const float* wv  = (const float*)d_in[9];
  const float* bv  = (const float*)d_in[10];
  const float* gw3 = (const float*)d_in[11];
  const float* gb3 = (const float*)d_in[12];
  float* out = (float*)d_out;
  char* ws = (char*)d_ws;

  ushort_t* Qb = (ushort_t*)(ws);               // 33,554,432 B  [B,C,P] bf16
  ushort_t* Kb = (ushort_t*)(ws + 33554432);    // 33,554,432 B  [B,H,P,128] bf16
  ushort_t* Vb = (ushort_t*)(ws + 67108864);    // 33,554,432 B  [B,H,P,128] bf16
  float* stats = (float*)(ws + 100663296);      // 768 groups x {s1,s2}

  hipMemsetAsync(stats, 0, 1536 * sizeof(float), stream);
  conv_gn<<<dim3(16, 64), 256, 0, stream>>>(x, wq, wk, wv, bq, bk, bv,
                                            Qb, Kb, Vb, stats);
  gn_apply<<<2048, 256, 0, stream>>>(Qb, stats, gw1, gb1, gw2, gb2, gw3, gb3);
  attn<<<dim3(64, 16), 256, 0, stream>>>(Qb, Kb, Vb, out);
}

// Round 4
// 409.474 us; speedup vs baseline: 1.4057x; 1.4057x over previous
//
#include <hip/hip_runtime.h>

typedef unsigned short ushort_t;
typedef float  f32x4   __attribute__((ext_vector_type(4)));
typedef float  f32x16  __attribute__((ext_vector_type(16)));
typedef __bf16 bf16x4  __attribute__((ext_vector_type(4)));
typedef __bf16 bf16x8  __attribute__((ext_vector_type(8)));
typedef unsigned uint2v __attribute__((ext_vector_type(2)));

#define MFMA16(a,b,c) __builtin_amdgcn_mfma_f32_16x16x32_bf16((a),(b),(c),0,0,0)
#define MFMA32(a,b,c) __builtin_amdgcn_mfma_f32_32x32x16_bf16((a),(b),(c),0,0,0)

__device__ __forceinline__ ushort_t f2bf(float f) {
  union { float f; unsigned u; } v; v.f = f;
  unsigned u = v.u;
  unsigned r = u + 0x7FFFu + ((u >> 16) & 1u);   // round-to-nearest-even
  return (ushort_t)(r >> 16);
}
__device__ __forceinline__ float bf2f(ushort_t s) {
  union { unsigned u; float f; } v; v.u = ((unsigned)s) << 16;
  return v.f;
}

// swap lanes 32-63 of a with lanes 0-31 of b (v_permlane32_swap_b32)
__device__ __forceinline__ void plswap(unsigned& a, unsigned& b) {
#if __has_builtin(__builtin_amdgcn_permlane32_swap)
  uint2v r = __builtin_amdgcn_permlane32_swap(a, b, false, false);
  a = r[0]; b = r[1];
#else
  asm("v_permlane32_swap_b32 %0, %1" : "+v"(a), "+v"(b));
#endif
}

// async global->LDS, 16B per lane. LDS dest is wave-uniform-base + lane*16;
// global src is per-lane (this is how the source-side swizzle is applied).
__device__ __forceinline__ void gload_lds16(const ushort_t* g, ushort_t* l) {
  __builtin_amdgcn_global_load_lds(
      (const __attribute__((address_space(1))) unsigned int*)g,
      (__attribute__((address_space(3))) unsigned int*)l, 16, 0, 0);
}

// ---------------------------------------------------------------------------
// Kernel 1: fused grouped conv (MFMA) + bias; x staged once per block (f32 ->
// bf16 transpose in LDS), loops 3 branches x 4 ngsub. Writes unnormalized y
// in final layouts; accumulates GroupNorm partial sums via atomics.
// grid (pc=16, g*b=64), 256 thr.
// Q branch -> [B][C][P]; K/V branches -> [B][H][P][128].
// ---------------------------------------------------------------------------
__global__ __launch_bounds__(256) void conv_gn(
    const float* __restrict__ x,
    const float* __restrict__ wq, const float* __restrict__ wk, const float* __restrict__ wv,
    const float* __restrict__ bq, const float* __restrict__ bk, const float* __restrict__ bv,
    ushort_t* __restrict__ Qb, ushort_t* __restrict__ Kb, ushort_t* __restrict__ Vb,
    float* __restrict__ stats) {
  int pc = blockIdx.x;
  int gz = blockIdx.y;
  int b = gz & 7, g = gz >> 3;
  int tid = threadIdx.x, lane = tid & 63, wid = tid >> 6;
  int l15 = lane & 15, q = lane >> 4;

  __shared__ __align__(16) ushort_t xl[128 * 72];   // [p][f]
  __shared__ __align__(16) ushort_t wl[128 * 72];   // [co][f], one branch
  __shared__ __align__(16) ushort_t yl[128 * 40];   // staging (br=0 uses [32][136])
  __shared__ float biasl[128];
  __shared__ float redbuf[8];

  // stage x tile [64 f][128 p] f32 -> xl[p][f] bf16
  const float* xsrc = x + ((size_t)(b * 512 + g * 64)) * 2048 + pc * 128;
#pragma unroll
  for (int r = 0; r < 8; ++r) {
    int chunk = tid + 256 * r;
    int c = chunk >> 5, p4 = chunk & 31;
    float4 v = *(const float4*)&xsrc[(size_t)c * 2048 + p4 * 4];
    xl[(p4 * 4 + 0) * 72 + c] = f2bf(v.x);
    xl[(p4 * 4 + 1) * 72 + c] = f2bf(v.y);
    xl[(p4 * 4 + 2) * 72 + c] = f2bf(v.z);
    xl[(p4 * 4 + 3) * 72 + c] = f2bf(v.w);
  }
  __syncthreads();

  // resident B-frags (wave's 32 p-cols)
  bf16x8 Bx[2][2];
#pragma unroll
  for (int n2 = 0; n2 < 2; ++n2)
#pragma unroll
    for (int kk = 0; kk < 2; ++kk)
      Bx[n2][kk] = *(const bf16x8*)&xl[((wid * 2 + n2) * 16 + l15) * 72 + kk * 32 + q * 8];

  for (int br = 0; br < 3; ++br) {
    const float* w    = (br == 0) ? wq : ((br == 1) ? wk : wv);
    const float* bias = (br == 0) ? bq : ((br == 1) ? bk : bv);
    ushort_t* dst     = (br == 0) ? Qb : ((br == 1) ? Kb : Vb);
    __syncthreads();   // previous branch's wl/yl consumers done
    const float* wsrc = w + (size_t)g * 128 * 64;
#pragma unroll
    for (int r = 0; r < 8; ++r) {
      int idx = (tid + 256 * r) << 2;
      float4 v = *(const float4*)&wsrc[idx];
      int row = idx >> 6, f = idx & 63;
      bf16x4 wv4 = {(__bf16)v.x, (__bf16)v.y, (__bf16)v.z, (__bf16)v.w};
      *(bf16x4*)&wl[row * 72 + f] = wv4;
    }
    if (tid < 128) biasl[tid] = bias[g * 128 + tid];
    __syncthreads();

    for (int ngs = 0; ngs < 4; ++ngs) {
      int co0 = ngs * 32;
      bf16x8 Aw[2][2];
#pragma unroll
      for (int m = 0; m < 2; ++m)
#pragma unroll
        for (int kk = 0; kk < 2; ++kk)
          Aw[m][kk] = *(const bf16x8*)&wl[(co0 + m * 16 + l15) * 72 + kk * 32 + q * 8];
      // acc[a][b]: br==0 (swapped): a = n2 (p-tile), b = mw (co-tile);
      //            br>=1:           a = m  (co),     b = n2 (p)
      f32x4 acc[2][2];
#pragma unroll
      for (int a = 0; a < 2; ++a)
#pragma unroll
        for (int c2 = 0; c2 < 2; ++c2) acc[a][c2] = (f32x4){0.f, 0.f, 0.f, 0.f};
      if (br == 0) {
#pragma unroll
        for (int kk = 0; kk < 2; ++kk)
#pragma unroll
          for (int n2 = 0; n2 < 2; ++n2)
#pragma unroll
            for (int mw = 0; mw < 2; ++mw)
              acc[n2][mw] = MFMA16(Bx[n2][kk], Aw[mw][kk], acc[n2][mw]);
      } else {
#pragma unroll
        for (int kk = 0; kk < 2; ++kk)
#pragma unroll
          for (int n2 = 0; n2 < 2; ++n2)
#pragma unroll
            for (int m = 0; m < 2; ++m)
              acc[m][n2] = MFMA16(Aw[m][kk], Bx[n2][kk], acc[m][n2]);
      }

      float s1 = 0.f, s2 = 0.f;
      if (br == 0) {   // c = co0 + mw*16 + l15 (one bias per frag)
#pragma unroll
        for (int n2 = 0; n2 < 2; ++n2)
#pragma unroll
          for (int mw = 0; mw < 2; ++mw) {
            float bi = biasl[co0 + mw * 16 + l15];
#pragma unroll
            for (int rg = 0; rg < 4; ++rg) {
              float y = acc[n2][mw][rg] + bi;
              acc[n2][mw][rg] = y;
              s1 += y; s2 += y * y;
            }
          }
      } else {         // c = co0 + m*16 + 4q + rg
#pragma unroll
        for (int m = 0; m < 2; ++m)
#pragma unroll
          for (int n2 = 0; n2 < 2; ++n2)
#pragma unroll
            for (int rg = 0; rg < 4; ++rg) {
              float y = acc[m][n2][rg] + biasl[co0 + m * 16 + 4 * q + rg];
              acc[m][n2][rg] = y;
              s1 += y; s2 += y * y;
            }
      }
#pragma unroll
      for (int mask = 32; mask >= 1; mask >>= 1) {
        s1 += __shfl_xor(s1, mask, 64);
        s2 += __shfl_xor(s2, mask, 64);
      }

      __syncthreads();   // previous ngs's yl global-store reads done
      if (lane == 0) { redbuf[wid * 2] = s1; redbuf[wid * 2 + 1] = s2; }
      if (br == 0) {   // yl: [32 c][136 p]; row = co_local (l15), cols = p (regs)
#pragma unroll
        for (int n2 = 0; n2 < 2; ++n2)
#pragma unroll
          for (int mw = 0; mw < 2; ++mw) {
            bf16x4 pk = {(__bf16)acc[n2][mw][0], (__bf16)acc[n2][mw][1],
                         (__bf16)acc[n2][mw][2], (__bf16)acc[n2][mw][3]};
            *(bf16x4*)&yl[(mw * 16 + l15) * 136 + (wid * 2 + n2) * 16 + 4 * q] = pk;
          }
      } else {         // yl: [128 p][40 c]; row = p (l15), cols = c (regs)
#pragma unroll
        for (int m = 0; m < 2; ++m)
#pragma unroll
          for (int n2 = 0; n2 < 2; ++n2) {
            bf16x4 pk = {(__bf16)acc[m][n2][0], (__bf16)acc[m][n2][1],
                         (__bf16)acc[m][n2][2], (__bf16)acc[m][n2][3]};
            *(bf16x4*)&yl[((wid * 2 + n2) * 16 + l15) * 40 + m * 16 + 4 * q] = pk;
          }
      }
      __syncthreads();

      if (br == 0) {
#pragma unroll
        for (int r = 0; r < 2; ++r) {
          int chunk = tid + 256 * r;
          int row = chunk >> 4, ch = chunk & 15;
          *(uint4*)&dst[((size_t)(b * 1024 + g * 128 + co0 + row)) * 2048 + pc * 128 + ch * 8] =
              *(const uint4*)&yl[row * 136 + ch * 8];
        }
      } else {
#pragma unroll
        for (int r = 0; r < 2; ++r) {
          int chunk = tid + 256 * r;
          int row = chunk >> 2, ch = chunk & 3;
          *(uint4*)&dst[((size_t)(b * 8 + g) * 2048 + pc * 128 + row) * 128 + co0 + ch * 8] =
              *(const uint4*)&yl[row * 40 + ch * 8];
        }
      }
      if (tid == 0) {
        float S1 = redbuf[0] + redbuf[2] + redbuf[4] + redbuf[6];
        float S2 = redbuf[1] + redbuf[3] + redbuf[5] + redbuf[7];
        int sidx = (br * 8 + b) * 32 + g * 4 + ngs;
        atomicAdd(&stats[2 * sidx], S1);
        atomicAdd(&stats[2 * sidx + 1], S2);
      }
    }
  }
}

// ---------------------------------------------------------------------------
// Kernel 2: in-place GroupNorm affine + LeakyReLU over the 3 contiguous bufs.
// grid-stride (2048 blocks x 12 iters).
// ---------------------------------------------------------------------------
__global__ __launch_bounds__(256) void gn_apply(
    ushort_t* __restrict__ buf, const float* __restrict__ stats,
    const float* __restrict__ gw1, const float* __restrict__ gb1,
    const float* __restrict__ gw2, const float* __restrict__ gb2,
    const float* __restrict__ gw3, const float* __restrict__ gb3) {
  const unsigned NQ = 16777216u;
  unsigned base = blockIdx.x * 256 + threadIdx.x;   // 524288 threads
  for (int itn = 0; itn < 12; ++itn) {
    unsigned gid = base + (unsigned)itn * 524288u;
    unsigned e = gid * 8;
    int br; unsigned local;
    if (e < NQ)            { br = 0; local = e; }
    else if (e < 2u * NQ)  { br = 1; local = e - NQ; }
    else                   { br = 2; local = e - 2u * NQ; }
    int b, c0;
    if (br == 0) { b = local >> 21; c0 = (local >> 11) & 1023; }
    else {
      int cih = local & 127; int h = (local >> 18) & 7;
      b = local >> 21; c0 = h * 128 + cih;
    }
    int ng = c0 >> 5;
    const float* gw = (br == 0) ? gw1 : ((br == 1) ? gw2 : gw3);
    const float* gb = (br == 0) ? gb1 : ((br == 1) ? gb2 : gb3);
    int sidx = (br * 8 + b) * 32 + ng;
    float mean = stats[2 * sidx] * (1.f / 65536.f);
    float var  = stats[2 * sidx + 1] * (1.f / 65536.f) - mean * mean;
    float rstd = rsqrtf(var + 1e-5f);
    uint4 d = *(uint4*)&buf[(size_t)e];
    ushort_t* pu = (ushort_t*)&d;
#pragma unroll
    for (int i = 0; i < 8; ++i) {
      int ci = (br == 0) ? c0 : (c0 + i);
      float a = rstd * gw[ci];
      float b2 = gb[ci] - mean * a;
      float yn = fmaf(bf2f(pu[i]), a, b2);
      yn = (yn >= 0.f) ? yn : 0.1f * yn;
      pu[i] = f2bf(yn);
    }
    *(uint4*)&buf[(size_t)e] = d;
  }
}

// ---------------------------------------------------------------------------
// Kernel 3: flash attention, 32x32x16 MFMA, S^T formulation.
// flashQ=K-branch [B,H,P,128] (i), flashK=V-branch [B,H,P,128] (j),
// flashV=Q-branch [B,C,P] (c rows, p=j cols).
// Block: i-tile 256 (4 waves x 64 i = 2 n-tiles), j-tile 32, grid (8,64).
//
// R9 = R6 (204us, proven 2-buffer __syncthreads pipeline) + de-risked R8
// ideas (R8 never benched: container died; suspects were the raw-barrier
// counted-vmcnt ring and asm permlane — both replaced/guarded here):
//  * T12 register-P: q2-half j-exchange via v_cvt_pk_bf16_f32 +
//    permlane32_swap (builtin w/ asm fallback). ST[rg] holds
//    j = 8*(rg>>2)+4*q2+(rg&3); for each jc: a=pk(0,1) c=pk(2,3)
//    b=pk(4,5) d=pk(6,7); swap(a,b), swap(c,d) -> frag {a',c',b',d'}
//    valid for BOTH q2 halves (k = q2*8+e). Removes all Ps LDS traffic
//    (8 ds_write + 4 ds_read/jt + its bank conflicts).
//  * XCD remap (in-kernel, grid unchanged): lin = bx + 8*by; XCD = lin%8.
//    it = (lin>>3)&7, bh = (lin&7) + 8*(lin>>6)  ->  XCD = bh&7, so the
//    8 it-blocks sharing one bh's fK/fV are co-resident on ONE XCD's L2
//    (R6 had XCD = it: zero same-XCD sharing -> FETCH 285MB = 2.85x ideal).
//  * T5 s_setprio(1) around both MFMA clusters.
//  * kept: global_load_lds staging w/ source-side XOR swizzles, defer-max,
//    exp2-domain softmax, launch_bounds(256,2) (VGPR 128 + acc — do NOT
//    use (256,4): forces 64 VGPR -> 24MB scratch spill, R7 lesson).
// LDS 32 KB, 2 blocks/CU.
// ---------------------------------------------------------------------------
__global__ __launch_bounds__(256, 2) void attn(
    const ushort_t* __restrict__ Qb, const ushort_t* __restrict__ Kb,
    const ushort_t* __restrict__ Vb, float* __restrict__ out) {
  __shared__ __align__(16) ushort_t fKs[2][32 * 128];   // [j][d] linear, 2x8192 B
  __shared__ __align__(16) ushort_t Vs[2][128 * 32];    // [c][j] linear, 2x8192 B

  int lin = blockIdx.x + 8 * blockIdx.y;           // XCD = lin % 8
  int it = (lin >> 3) & 7;
  int bh = (lin & 7) + 8 * (lin >> 6);             // XCD = bh & 7
  int b = bh >> 3, h = bh & 7;
  int tid = threadIdx.x, lane = tid & 63, wid = tid >> 6;
  int l31 = lane & 31, q2 = lane >> 5;
  // scale*log2(e): softmax in exp2 domain
  const float sl = 0.08838834764831845f * 1.4426950408889634f;

  // resident fQ B-frags: B[k=d][n=i], n-col = l31 -> row i (one-time load)
  bf16x8 Bq[2][8];
#pragma unroll
  for (int nt = 0; nt < 2; ++nt) {
    const ushort_t* fQp =
        Kb + ((size_t)bh * 2048 + it * 256 + wid * 64 + nt * 32 + l31) * 128 + q2 * 8;
#pragma unroll
    for (int dc = 0; dc < 8; ++dc) Bq[nt][dc] = *(const bf16x8*)&fQp[dc * 16];
  }

  float m2[2], l_i[2];
  m2[0] = m2[1] = -3e38f;
  l_i[0] = l_i[1] = 0.f;
  f32x16 O[4][2];
#pragma unroll
  for (int mt = 0; mt < 4; ++mt)
#pragma unroll
    for (int nt = 0; nt < 2; ++nt) O[mt][nt] = (f32x16)(0.f);

  const ushort_t* fKg = Vb + (size_t)bh * 2048 * 128;
  const ushort_t* fVg = Qb + ((size_t)(b * 1024 + h * 128)) * 2048;

  // ---- staging: 512 16B-units per tensor-tile; each thread issues 2+2.
  // LDS is linear in unit index n (wave-uniform base + lane*16); the XOR
  // swizzle is applied to the unit index on the GLOBAL side.
#define STAGE(JT, NB)                                                          \
  do {                                                                         \
    _Pragma("unroll")                                                          \
    for (int r = 0; r < 2; ++r) {                                              \
      int n = tid + 256 * r;                                                   \
      int kr = n >> 4, ku = (n & 15) ^ (kr & 7);                               \
      gload_lds16(fKg + (size_t)(JT) * 4096 + kr * 128 + ku * 8,               \
                  &fKs[NB][n * 8]);                                            \
      int vr = n >> 2, vu = (n & 3) ^ ((vr >> 1) & 3);                         \
      gload_lds16(fVg + (size_t)vr * 2048 + (JT) * 32 + vu * 8,                \
                  &Vs[NB][n * 8]);                                             \
    }                                                                          \
  } while (0)

  STAGE(0, 0);
  __syncthreads();   // vmcnt(0) drain + barrier: tile 0 visible
  int cur = 0;

  for (int jt = 0; jt < 64; ++jt) {
    if (jt < 63) STAGE(jt + 1, cur ^ 1);   // async prefetch into idle buffer

    // S^T = fK . fQ^T : 8 swizzled A-reads, 16 MFMAs
    f32x16 ST[2];
    ST[0] = (f32x16)(0.f);
    ST[1] = (f32x16)(0.f);
    __builtin_amdgcn_s_setprio(1);
#pragma unroll
    for (int dc = 0; dc < 8; ++dc) {
      int up = (dc * 2 + q2) ^ (l31 & 7);
      bf16x8 Ak = *(const bf16x8*)&fKs[cur][l31 * 128 + up * 8];
      ST[0] = MFMA32(Ak, Bq[0][dc], ST[0]);
      ST[1] = MFMA32(Ak, Bq[1][dc], ST[1]);
    }
    __builtin_amdgcn_s_setprio(0);

    // online softmax over j; lane covers i (j split across q2).
    // P -> bf16 MFMA B-frags IN REGISTER via cvt_pk + permlane32_swap.
    bf16x8 Bp[2][2];   // [nt][jc]
#pragma unroll
    for (int nt = 0; nt < 2; ++nt) {
      float vmax = ST[nt][0];
#pragma unroll
      for (int rg = 1; rg < 16; ++rg) vmax = fmaxf(vmax, ST[nt][rg]);
      float v2 = vmax * sl;
      v2 = fmaxf(v2, __shfl_xor(v2, 32, 64));
      float al = 1.f;
      bool need = !__all(v2 <= m2[nt] + 8.f);   // defer-max: wave-uniform
      if (need) {
        float mn2 = fmaxf(m2[nt], v2);
        al = __builtin_amdgcn_exp2f(m2[nt] - mn2);
        m2[nt] = mn2;
      }
      float mn = m2[nt];
      float p16[16];
      float rs = 0.f;
#pragma unroll
      for (int rg = 0; rg < 16; ++rg) {
        p16[rg] = __builtin_amdgcn_exp2f(fmaf(ST[nt][rg], sl, -mn));
        rs += p16[rg];
      }
      rs += __shfl_xor(rs, 32, 64);
      l_i[nt] = l_i[nt] * al + rs;
      if (need) {   // O rescale only when running max moved (i on lanes)
#pragma unroll
        for (int mt = 0; mt < 4; ++mt)
#pragma unroll
          for (int rg = 0; rg < 16; ++rg) O[mt][nt][rg] *= al;
      }
#pragma unroll
      for (int jc = 0; jc < 2; ++jc) {
        unsigned pa, pb, pc_, pd;
        asm("v_cvt_pk_bf16_f32 %0, %1, %2"
            : "=v"(pa) : "v"(p16[jc * 8 + 0]), "v"(p16[jc * 8 + 1]));
        asm("v_cvt_pk_bf16_f32 %0, %1, %2"
            : "=v"(pc_) : "v"(p16[jc * 8 + 2]), "v"(p16[jc * 8 + 3]));
        asm("v_cvt_pk_bf16_f32 %0, %1, %2"
            : "=v"(pb) : "v"(p16[jc * 8 + 4]), "v"(p16[jc * 8 + 5]));
        asm("v_cvt_pk_bf16_f32 %0, %1, %2"
            : "=v"(pd) : "v"(p16[jc * 8 + 6]), "v"(p16[jc * 8 + 7]));
        plswap(pa, pb);
        plswap(pc_, pd);
        union { unsigned u[4]; bf16x8 v; } fr;
        fr.u[0] = pa; fr.u[1] = pc_; fr.u[2] = pb; fr.u[3] = pd;
        Bp[nt][jc] = fr.v;
      }
    }

    // O^T += V . P^T : 8 swizzled V-reads, 16 MFMAs (P in registers)
    __builtin_amdgcn_s_setprio(1);
#pragma unroll
    for (int jc = 0; jc < 2; ++jc) {
#pragma unroll
      for (int mt = 0; mt < 4; ++mt) {
        int row = mt * 32 + l31;
        int up = (jc * 2 + q2) ^ ((row >> 1) & 3);
        bf16x8 Av = *(const bf16x8*)&Vs[cur][row * 32 + up * 8];
        O[mt][0] = MFMA32(Av, Bp[0][jc], O[mt][0]);
        O[mt][1] = MFMA32(Av, Bp[1][jc], O[mt][1]);
      }
    }
    __builtin_amdgcn_s_setprio(0);
    __syncthreads();   // single barrier: prefetch complete + all reads done
    cur ^= 1;
  }
#undef STAGE

  // epilogue: i on lanes -> direct coalesced stores
  float linv[2];
  linv[0] = 1.f / l_i[0];
  linv[1] = 1.f / l_i[1];
#pragma unroll
  for (int mt = 0; mt < 4; ++mt)
#pragma unroll
    for (int nt = 0; nt < 2; ++nt) {
      float* obase = out + ((size_t)(b * 1024 + h * 128 + mt * 32)) * 2048 +
                     it * 256 + wid * 64 + nt * 32 + l31;
#pragma unroll
      for (int rg = 0; rg < 16; ++rg) {
        int c = (rg & 3) + 8 * (rg >> 2) + 4 * q2;
        obase[(size_t)c * 2048] = O[mt][nt][rg] * linv[nt];
      }
    }
}

// ---------------------------------------------------------------------------
extern "C" void kernel_launch(void* const* d_in, const int* in_sizes, int n_in,
                              void* d_out, int out_size, void* d_ws, size_t ws_size,
                              hipStream_t stream) {
  const float* x   = (const float*)d_in[0];
  const float* wq  = (const float*)d_in[1];
  const float* bq  = (const float*)d_in[2];
  const float* gw1 = (const float*)d_in[3];
  const float* gb1 = (const float*)d_in[4];
  const float* wk  = (const float*)d_in[5];
  const float* bk  = (const float*)d_in[6];
  const float* gw2 = (const float*)d_in[7];
  const float* gb2 = (const float*)d_in[8];
  const float* wv  = (const float*)d_in[9];
  const float* bv  = (const float*)d_in[10];
  const float* gw3 = (const float*)d_in[11];
  const float* gb3 = (const float*)d_in[12];
  float* out = (float*)d_out;
  char* ws = (char*)d_ws;

  ushort_t* Qb = (ushort_t*)(ws);               // 33,554,432 B  [B,C,P] bf16
  ushort_t* Kb = (ushort_t*)(ws + 33554432);    // 33,554,432 B  [B,H,P,128] bf16
  ushort_t* Vb = (ushort_t*)(ws + 67108864);    // 33,554,432 B  [B,H,P,128] bf16
  float* stats = (float*)(ws + 100663296);      // 768 groups x {s1,s2}

  hipMemsetAsync(stats, 0, 1536 * sizeof(float), stream);
  conv_gn<<<dim3(16, 64), 256, 0, stream>>>(x, wq, wk, wv, bq, bk, bv,
                                            Qb, Kb, Vb, stats);
  gn_apply<<<2048, 256, 0, stream>>>(Qb, stats, gw1, gb1, gw2, gb2, gw3, gb3);
  attn<<<dim3(8, 64), 256, 0, stream>>>(Qb, Kb, Vb, out);
}